// Round 5
// baseline (1632.066 us; speedup 1.0000x reference)
//
#include <hip/hip_runtime.h>
#include <hip/hip_bf16.h>
#include <cstdint>
#include <cstddef>

#define DD 64

typedef __attribute__((ext_vector_type(8))) short short8;
typedef __attribute__((ext_vector_type(4))) float f32x4;

__device__ __forceinline__ float4 f4_0() { return make_float4(0.f, 0.f, 0.f, 0.f); }

__device__ __forceinline__ unsigned short f2bf(float f) {
  __hip_bfloat16 h = __float2bfloat16(f);
  return *reinterpret_cast<unsigned short*>(&h);
}
__device__ __forceinline__ float bfl(unsigned u) {  // low bf16 of a uint
  return __uint_as_float(u << 16);
}
__device__ __forceinline__ float bfh(unsigned u) {  // high bf16 of a uint
  return __uint_as_float(u & 0xffff0000u);
}
__device__ __forceinline__ float b2f(unsigned short u) {
  return __uint_as_float(((unsigned)u) << 16);
}

__device__ __forceinline__ short8 pack_bf16x8(float4 a, float4 b) {
  union { unsigned short us[8]; short8 v; } pk;
  pk.us[0] = f2bf(a.x); pk.us[1] = f2bf(a.y); pk.us[2] = f2bf(a.z); pk.us[3] = f2bf(a.w);
  pk.us[4] = f2bf(b.x); pk.us[5] = f2bf(b.y); pk.us[6] = f2bf(b.z); pk.us[7] = f2bf(b.w);
  return pk.v;
}

__device__ __forceinline__ short8 lds_frag(const unsigned short* p) {
  uint2 lo = *reinterpret_cast<const uint2*>(p);
  uint2 hi = *reinterpret_cast<const uint2*>(p + 4);
  union { unsigned u[4]; short8 v; } t;
  t.u[0] = lo.x; t.u[1] = lo.y; t.u[2] = hi.x; t.u[3] = hi.y;
  return t.v;
}

// ---------- row GEMM (fp32, node-side) ----------
__device__ __forceinline__ void row_gemm64(const float* __restrict__ row,
                                           const float* __restrict__ W,
                                           float acc[DD]) {
  for (int k4 = 0; k4 < DD; k4 += 4) {
    const float4 rv = *reinterpret_cast<const float4*>(row + k4);
    const float rvals[4] = {rv.x, rv.y, rv.z, rv.w};
#pragma unroll
    for (int kk = 0; kk < 4; ++kk) {
      const float v = rvals[kk];
      const float* wr = W + (k4 + kk) * DD;
#pragma unroll
      for (int d = 0; d < DD; ++d) acc[d] = fmaf(v, wr[d], acc[d]);
    }
  }
}

__device__ __forceinline__ void init_bias64(const float* __restrict__ b, float acc[DD]) {
#pragma unroll
  for (int d = 0; d < DD; ++d) acc[d] = b[d];
}

// ---------- CSR build ----------
__global__ __launch_bounds__(256) void k_hist(const int* __restrict__ dst,
                                              int* __restrict__ cnt, int E) {
  int j = blockIdx.x * 256 + threadIdx.x;
  if (j < E) atomicAdd(&cnt[dst[j]], 1);
}

__global__ __launch_bounds__(1024) void k_scan(const int* __restrict__ cnt,
                                               int* __restrict__ row_ptr,
                                               int* __restrict__ nxt, int N, int E) {
  __shared__ int wsum[16];
  __shared__ int carry_s;
  const int tid = threadIdx.x;
  const int wid = tid >> 6, lane = tid & 63;
  if (tid == 0) carry_s = 0;
  __syncthreads();
  const int nt = (N + 1023) / 1024;
  for (int b = 0; b < nt; ++b) {
    int i = b * 1024 + tid;
    int v = (i < N) ? cnt[i] : 0;
    int x = v;
#pragma unroll
    for (int off = 1; off < 64; off <<= 1) {
      int y = __shfl_up(x, off, 64);
      if (lane >= off) x += y;
    }
    if (lane == 63) wsum[wid] = x;
    __syncthreads();
    if (wid == 0 && lane < 16) {
      int wv = wsum[lane];
#pragma unroll
      for (int off = 1; off < 16; off <<= 1) {
        int y = __shfl_up(wv, off, 64);
        if (lane >= off) wv += y;
      }
      wsum[lane] = wv;
    }
    __syncthreads();
    int base = carry_s + (wid > 0 ? wsum[wid - 1] : 0);
    int excl = base + x - v;
    if (i < N) { row_ptr[i] = excl; nxt[i] = excl; }
    __syncthreads();
    if (tid == 0) carry_s += wsum[15];
    __syncthreads();
  }
  if (tid == 0) row_ptr[N] = E;
}

// scatter also builds permuted src/dst so all edge kernels run in CSR order
__global__ __launch_bounds__(256) void k_scatter(const int* __restrict__ dst,
                                                 const int* __restrict__ src,
                                                 int* __restrict__ nxt,
                                                 int* __restrict__ order,
                                                 int* __restrict__ psrc,
                                                 int* __restrict__ pdst, int E) {
  int j = blockIdx.x * 256 + threadIdx.x;
  if (j >= E) return;
  int d = dst[j];
  int pos = atomicAdd(&nxt[d], 1);
  order[pos] = j;
  psrc[pos] = src[j];
  pdst[pos] = d;
}

// ---------- conv1d + maxpool via bf16 MFMA (unchanged, verified) ----------
__global__ __launch_bounds__(256) void k_conv_mfma(const float* __restrict__ reads,
                                                   const float* __restrict__ w,
                                                   const float* __restrict__ bias,
                                                   float* __restrict__ h, int N) {
  __shared__ unsigned short cp[4 * 4 * 4 * 144];  // [node][c][s][144]
  const int tid = threadIdx.x;
  const int nb = blockIdx.x * 4;
  for (int task = tid; task < 576; task += 256) {
    const int node = task / 144;
    const int rem = task % 144;
    const int c = rem / 36;
    const int u = rem % 36;
    const int gn = nb + node;
    float4 v0 = f4_0(), v1 = f4_0();
    if (gn < N) {
      const float* rp = reads + (size_t)gn * 512 + c * 128 + 4 * u;
      if (u <= 31) v0 = *reinterpret_cast<const float4*>(rp);
      if (u <= 30) v1 = *reinterpret_cast<const float4*>(rp + 4);
    }
    unsigned short us[8];
    us[0] = f2bf(v0.x); us[1] = f2bf(v0.y); us[2] = f2bf(v0.z); us[3] = f2bf(v0.w);
    us[4] = f2bf(v1.x); us[5] = f2bf(v1.y); us[6] = f2bf(v1.z); us[7] = f2bf(v1.w);
    const int base = ((node * 4 + c) * 4) * 144 + 4 * u;
#pragma unroll
    for (int s = 0; s < 4; ++s) {
      uint2 pk;
      pk.x = (unsigned)us[s] | ((unsigned)us[s + 1] << 16);
      pk.y = (unsigned)us[s + 2] | ((unsigned)us[s + 3] << 16);
      *reinterpret_cast<uint2*>(&cp[base + s * 144]) = pk;
    }
  }
  __syncthreads();
  const int wid = tid >> 6, lane = tid & 63;
  const int gn = nb + wid;
  if (gn >= N) return;
  const int col = lane & 15, grp = lane >> 4;
  short8 af[4][2];
#pragma unroll
  for (int mt = 0; mt < 4; ++mt)
#pragma unroll
    for (int ks = 0; ks < 2; ++ks) {
      const int d = col + 16 * mt;
      const int kb = ks * 32 + grp * 8;
      const float* wp = w + d * 64 + kb;
      float4 w0 = *reinterpret_cast<const float4*>(wp);
      float4 w1 = *reinterpret_cast<const float4*>(wp + 4);
      af[mt][ks] = pack_bf16x8(w0, w1);
    }
  float vmax[4][4];
#pragma unroll
  for (int mt = 0; mt < 4; ++mt)
#pragma unroll
    for (int r = 0; r < 4; ++r) vmax[mt][r] = -3.0e38f;
  const int s = col & 3;
  for (int ntile = 0; ntile < 8; ++ntile) {
    const int t = ntile * 16 + col;
    f32x4 acc[4] = {};
#pragma unroll
    for (int ks = 0; ks < 2; ++ks) {
      const int kbase = ks * 32 + grp * 8;
      const int c = kbase >> 4;
      const int kk0 = kbase & 15;
      const int q = (t - s) + kk0;
      const unsigned short* p = &cp[((wid * 4 + c) * 4 + s) * 144 + q];
      short8 bb = lds_frag(p);
#pragma unroll
      for (int mt = 0; mt < 4; ++mt)
        acc[mt] = __builtin_amdgcn_mfma_f32_16x16x32_bf16(af[mt][ks], bb, acc[mt], 0, 0, 0);
    }
    if (t < 113) {
#pragma unroll
      for (int mt = 0; mt < 4; ++mt)
#pragma unroll
        for (int r = 0; r < 4; ++r) vmax[mt][r] = fmaxf(vmax[mt][r], acc[mt][r]);
    }
  }
#pragma unroll
  for (int off = 8; off >= 1; off >>= 1)
#pragma unroll
    for (int mt = 0; mt < 4; ++mt)
#pragma unroll
      for (int r = 0; r < 4; ++r)
        vmax[mt][r] = fmaxf(vmax[mt][r], __shfl_xor(vmax[mt][r], off, 64));
  if (col == 0) {
#pragma unroll
    for (int mt = 0; mt < 4; ++mt)
#pragma unroll
      for (int r = 0; r < 4; ++r) {
        const int d = mt * 16 + grp * 4 + r;
        h[(size_t)gn * 64 + d] = vmax[mt][r] + bias[d];
      }
  }
}

// ---------- edge encoder (writes e in PERMUTED layout) ----------
__global__ __launch_bounds__(256) void k_edge_enc(const float* __restrict__ sim,
                                                  const float* __restrict__ len,
                                                  const int* __restrict__ order,
                                                  const float* __restrict__ We,
                                                  const float* __restrict__ be,
                                                  float* __restrict__ e, int E) {
  int idx = blockIdx.x * 256 + threadIdx.x;
  if (idx >= E * 16) return;
  int j = idx >> 4, dc = (idx & 15) << 2;
  int oj = order[j];
  float s = sim[oj], L = len[oj];
  float4 w0 = *reinterpret_cast<const float4*>(We + dc);
  float4 w1 = *reinterpret_cast<const float4*>(We + 64 + dc);
  float4 b  = *reinterpret_cast<const float4*>(be + dc);
  float4 o;
  o.x = fmaf(s, w0.x, fmaf(L, w1.x, b.x));
  o.y = fmaf(s, w0.y, fmaf(L, w1.y, b.y));
  o.z = fmaf(s, w0.z, fmaf(L, w1.z, b.z));
  o.w = fmaf(s, w0.w, fmaf(L, w1.w, b.w));
  *reinterpret_cast<float4*>(e + (size_t)j * 64 + dc) = o;
}

// ---------- node GEMMs (fp32 compute, bf16 output) ----------
__global__ __launch_bounds__(256) void k_node_gemm(const float* __restrict__ h,
                                                   const float* __restrict__ Wa,
                                                   const float* __restrict__ Wb,
                                                   const float* __restrict__ Wc,
                                                   const float* __restrict__ ba,
                                                   const float* __restrict__ bb,
                                                   const float* __restrict__ bc,
                                                   unsigned short* __restrict__ Xa,
                                                   unsigned short* __restrict__ Xb,
                                                   unsigned short* __restrict__ Xc, int N) {
  const float* W; const float* bi; unsigned short* X;
  if (blockIdx.y == 0)      { W = Wa; bi = ba; X = Xa; }
  else if (blockIdx.y == 1) { W = Wb; bi = bb; X = Xb; }
  else                      { W = Wc; bi = bc; X = Xc; }
  int n = blockIdx.x * 256 + threadIdx.x;
  if (n >= N) return;
  float acc[DD];
  init_bias64(bi, acc);
  row_gemm64(h + (size_t)n * 64, W, acc);
#pragma unroll
  for (int d8 = 0; d8 < DD; d8 += 8) {
    uint4 pk;
    pk.x = (unsigned)f2bf(acc[d8 + 0]) | ((unsigned)f2bf(acc[d8 + 1]) << 16);
    pk.y = (unsigned)f2bf(acc[d8 + 2]) | ((unsigned)f2bf(acc[d8 + 3]) << 16);
    pk.z = (unsigned)f2bf(acc[d8 + 4]) | ((unsigned)f2bf(acc[d8 + 5]) << 16);
    pk.w = (unsigned)f2bf(acc[d8 + 6]) | ((unsigned)f2bf(acc[d8 + 7]) << 16);
    *reinterpret_cast<uint4*>(X + (size_t)n * 64 + d8) = pk;
  }
}

// ---------- persistent edge MFMA, fused previous-layer e-update ----------
// Applies e += relu(coef_prev ⊙ ehat_prev) in-register (when hasupd), writes e,
// computes ehat = A3^T·e + XA1[psrc] + XA2[pdst] + bA3, writes ehat bf16.
__global__ __launch_bounds__(256) void k_edge_mfma(float* __restrict__ e,
                                                   const unsigned short* __restrict__ ehat_prev,
                                                   unsigned short* __restrict__ ehat_out,
                                                   const float* __restrict__ sums_prev,
                                                   const float* __restrict__ gprev,
                                                   const float* __restrict__ bprev,
                                                   const int* __restrict__ psrc,
                                                   const int* __restrict__ pdst,
                                                   const unsigned short* __restrict__ XA1,
                                                   const unsigned short* __restrict__ XA2,
                                                   const float* __restrict__ A3,
                                                   const float* __restrict__ bA3,
                                                   int E, int hasupd) {
  __shared__ unsigned short At[64 * 72];
  __shared__ float s_coef[128];
  const int tid = threadIdx.x;
  if (hasupd && tid < 64) {
    float mean = sums_prev[tid] / (float)E;
    float var = sums_prev[64 + tid] / (float)E - mean * mean;
    float sc = gprev[tid] * rsqrtf(var + 1e-5f);
    s_coef[tid] = sc;
    s_coef[64 + tid] = bprev[tid] - mean * sc;
  }
  for (int i = tid; i < 4096; i += 256) {
    int n = i & 63, k = i >> 6;
    At[n * 72 + k] = f2bf(A3[k * 64 + n]);
  }
  __syncthreads();
  const int wid = tid >> 6, lane = tid & 63;
  const int col = lane & 15, g = lane >> 4;
  short8 aa[4][2];
#pragma unroll
  for (int mt = 0; mt < 4; ++mt)
#pragma unroll
    for (int ks = 0; ks < 2; ++ks)
      aa[mt][ks] = lds_frag(&At[(mt * 16 + col) * 72 + ks * 32 + g * 8]);
  float4 ba[4];
#pragma unroll
  for (int mt = 0; mt < 4; ++mt)
    ba[mt] = *reinterpret_cast<const float4*>(bA3 + mt * 16 + g * 4);
  const int ntiles = (E + 15) / 16;
  for (int tw = blockIdx.x * 4 + wid; tw < ntiles; tw += gridDim.x * 4) {
    int p = tw * 16 + col;
    const bool valid = p < E;
    if (!valid) p = E - 1;
    const int se = psrc[p], de = pdst[p];
    short8 bfr[2];
#pragma unroll
    for (int ks = 0; ks < 2; ++ks) {
      float* ep = e + (size_t)p * 64 + ks * 32 + g * 8;
      float4 e0 = *reinterpret_cast<const float4*>(ep);
      float4 e1 = *reinterpret_cast<const float4*>(ep + 4);
      if (hasupd) {
        const int c0 = ks * 32 + g * 8;
        uint4 hv = *reinterpret_cast<const uint4*>(ehat_prev + (size_t)p * 64 + c0);
        float4 sc0 = *reinterpret_cast<const float4*>(&s_coef[c0]);
        float4 sc1 = *reinterpret_cast<const float4*>(&s_coef[c0 + 4]);
        float4 sh0 = *reinterpret_cast<const float4*>(&s_coef[64 + c0]);
        float4 sh1 = *reinterpret_cast<const float4*>(&s_coef[64 + c0 + 4]);
        e0.x += fmaxf(fmaf(sc0.x, bfl(hv.x), sh0.x), 0.f);
        e0.y += fmaxf(fmaf(sc0.y, bfh(hv.x), sh0.y), 0.f);
        e0.z += fmaxf(fmaf(sc0.z, bfl(hv.y), sh0.z), 0.f);
        e0.w += fmaxf(fmaf(sc0.w, bfh(hv.y), sh0.w), 0.f);
        e1.x += fmaxf(fmaf(sc1.x, bfl(hv.z), sh1.x), 0.f);
        e1.y += fmaxf(fmaf(sc1.y, bfh(hv.z), sh1.y), 0.f);
        e1.z += fmaxf(fmaf(sc1.z, bfl(hv.w), sh1.z), 0.f);
        e1.w += fmaxf(fmaf(sc1.w, bfh(hv.w), sh1.w), 0.f);
        if (valid) {
          *reinterpret_cast<float4*>(ep) = e0;
          *reinterpret_cast<float4*>(ep + 4) = e1;
        }
      }
      bfr[ks] = pack_bf16x8(e0, e1);
    }
    f32x4 acc[4] = {};
#pragma unroll
    for (int ks = 0; ks < 2; ++ks)
#pragma unroll
      for (int mt = 0; mt < 4; ++mt)
        acc[mt] = __builtin_amdgcn_mfma_f32_16x16x32_bf16(aa[mt][ks], bfr[ks], acc[mt], 0, 0, 0);
    if (valid) {
#pragma unroll
      for (int mt = 0; mt < 4; ++mt) {
        const int chb = mt * 16 + g * 4;
        ushort4 x1 = *reinterpret_cast<const ushort4*>(XA1 + (size_t)se * 64 + chb);
        ushort4 x2 = *reinterpret_cast<const ushort4*>(XA2 + (size_t)de * 64 + chb);
        float o0 = acc[mt][0] + b2f(x1.x) + b2f(x2.x) + ba[mt].x;
        float o1 = acc[mt][1] + b2f(x1.y) + b2f(x2.y) + ba[mt].y;
        float o2 = acc[mt][2] + b2f(x1.z) + b2f(x2.z) + ba[mt].z;
        float o3 = acc[mt][3] + b2f(x1.w) + b2f(x2.w) + ba[mt].w;
        ushort4 ov;
        ov.x = f2bf(o0); ov.y = f2bf(o1); ov.z = f2bf(o2); ov.w = f2bf(o3);
        *reinterpret_cast<ushort4*>(ehat_out + (size_t)p * 64 + chb) = ov;
      }
    }
  }
}

// ---------- per-channel stats over bf16 rows ----------
__global__ __launch_bounds__(256) void k_stats_bf16(const unsigned short* __restrict__ X,
                                                    int R, float* __restrict__ sums) {
  __shared__ float red[2][16][64];
  int tid = threadIdx.x;
  int g = tid >> 4, dc = (tid & 15) << 2;
  float4 s = f4_0(), q = f4_0();
  for (int r = blockIdx.x * 16 + g; r < R; r += gridDim.x * 16) {
    uint2 v = *reinterpret_cast<const uint2*>(X + (size_t)r * 64 + dc);
    float v0 = bfl(v.x), v1 = bfh(v.x), v2 = bfl(v.y), v3 = bfh(v.y);
    s.x += v0; s.y += v1; s.z += v2; s.w += v3;
    q.x = fmaf(v0, v0, q.x); q.y = fmaf(v1, v1, q.y);
    q.z = fmaf(v2, v2, q.z); q.w = fmaf(v3, v3, q.w);
  }
  *reinterpret_cast<float4*>(&red[0][g][dc]) = s;
  *reinterpret_cast<float4*>(&red[1][g][dc]) = q;
  __syncthreads();
  if (g == 0) {
    float4 ts = f4_0(), tq = f4_0();
#pragma unroll
    for (int gg = 0; gg < 16; ++gg) {
      float4 a = *reinterpret_cast<const float4*>(&red[0][gg][dc]);
      float4 b = *reinterpret_cast<const float4*>(&red[1][gg][dc]);
      ts.x += a.x; ts.y += a.y; ts.z += a.z; ts.w += a.w;
      tq.x += b.x; tq.y += b.y; tq.z += b.z; tq.w += b.w;
    }
    atomicAdd(&sums[dc], ts.x); atomicAdd(&sums[dc + 1], ts.y);
    atomicAdd(&sums[dc + 2], ts.z); atomicAdd(&sums[dc + 3], ts.w);
    atomicAdd(&sums[64 + dc], tq.x); atomicAdd(&sums[64 + dc + 1], tq.y);
    atomicAdd(&sums[64 + dc + 2], tq.z); atomicAdd(&sums[64 + dc + 3], tq.w);
  }
}

// ---------- per-channel stats over fp32 rows (hhat) ----------
__global__ __launch_bounds__(256) void k_stats(const float* __restrict__ X, int R,
                                               float* __restrict__ sums) {
  __shared__ float red[2][16][64];
  int tid = threadIdx.x;
  int g = tid >> 4, dc = (tid & 15) << 2;
  float4 s = f4_0(), q = f4_0();
  for (int r = blockIdx.x * 16 + g; r < R; r += gridDim.x * 16) {
    float4 v = *reinterpret_cast<const float4*>(X + (size_t)r * 64 + dc);
    s.x += v.x; s.y += v.y; s.z += v.z; s.w += v.w;
    q.x = fmaf(v.x, v.x, q.x); q.y = fmaf(v.y, v.y, q.y);
    q.z = fmaf(v.z, v.z, q.z); q.w = fmaf(v.w, v.w, q.w);
  }
  *reinterpret_cast<float4*>(&red[0][g][dc]) = s;
  *reinterpret_cast<float4*>(&red[1][g][dc]) = q;
  __syncthreads();
  if (g == 0) {
    float4 ts = f4_0(), tq = f4_0();
#pragma unroll
    for (int gg = 0; gg < 16; ++gg) {
      float4 a = *reinterpret_cast<const float4*>(&red[0][gg][dc]);
      float4 b = *reinterpret_cast<const float4*>(&red[1][gg][dc]);
      ts.x += a.x; ts.y += a.y; ts.z += a.z; ts.w += a.w;
      tq.x += b.x; tq.y += b.y; tq.z += b.z; tq.w += b.w;
    }
    atomicAdd(&sums[dc], ts.x); atomicAdd(&sums[dc + 1], ts.y);
    atomicAdd(&sums[dc + 2], ts.z); atomicAdd(&sums[dc + 3], ts.w);
    atomicAdd(&sums[64 + dc], tq.x); atomicAdd(&sums[64 + dc + 1], tq.y);
    atomicAdd(&sums[64 + dc + 2], tq.z); atomicAdd(&sums[64 + dc + 3], tq.w);
  }
}

// ---------- aggregation (sequential CSR rows, no e-touch) ----------
__global__ __launch_bounds__(256) void k_aggregate(const int* __restrict__ row_ptr,
                                                   const int* __restrict__ psrc,
                                                   const unsigned short* __restrict__ ehat,
                                                   const unsigned short* __restrict__ XV,
                                                   float* __restrict__ num,
                                                   float* __restrict__ den, int N) {
  int idx = blockIdx.x * 256 + threadIdx.x;
  if (idx >= N * 16) return;
  int n = idx >> 4, dc = (idx & 15) << 2;
  int beg = row_ptr[n], end = row_ptr[n + 1];
  float4 nm = f4_0(), dn = f4_0();
  for (int i = beg; i < end; ++i) {
    int sj = psrc[i];
    uint2 ev = *reinterpret_cast<const uint2*>(ehat + (size_t)i * 64 + dc);
    uint2 vv = *reinterpret_cast<const uint2*>(XV + (size_t)sj * 64 + dc);
    float s0 = 1.f / (1.f + __expf(-bfl(ev.x)));
    float s1 = 1.f / (1.f + __expf(-bfh(ev.x)));
    float s2 = 1.f / (1.f + __expf(-bfl(ev.y)));
    float s3 = 1.f / (1.f + __expf(-bfh(ev.y)));
    dn.x += s0; dn.y += s1; dn.z += s2; dn.w += s3;
    nm.x = fmaf(s0, bfl(vv.x), nm.x);
    nm.y = fmaf(s1, bfh(vv.x), nm.y);
    nm.z = fmaf(s2, bfl(vv.y), nm.z);
    nm.w = fmaf(s3, bfh(vv.y), nm.w);
  }
  *reinterpret_cast<float4*>(num + (size_t)n * 64 + dc) = nm;
  *reinterpret_cast<float4*>(den + (size_t)n * 64 + dc) = dn;
}

// ---------- h_hat (fp32) ----------
__global__ __launch_bounds__(256) void k_hhat(const float* __restrict__ h,
                                              const float* __restrict__ Uw,
                                              const float* __restrict__ bU,
                                              const float* __restrict__ num,
                                              const float* __restrict__ den,
                                              float* __restrict__ hhat, int N) {
  int n = blockIdx.x * 256 + threadIdx.x;
  if (n >= N) return;
  float acc[DD];
  init_bias64(bU, acc);
  row_gemm64(h + (size_t)n * 64, Uw, acc);
#pragma unroll
  for (int dc = 0; dc < DD; dc += 4) {
    float4 nm = *reinterpret_cast<const float4*>(num + (size_t)n * 64 + dc);
    float4 dn = *reinterpret_cast<const float4*>(den + (size_t)n * 64 + dc);
    float4 o = make_float4(acc[dc] + nm.x / (dn.x + 1e-6f),
                           acc[dc + 1] + nm.y / (dn.y + 1e-6f),
                           acc[dc + 2] + nm.z / (dn.z + 1e-6f),
                           acc[dc + 3] + nm.w / (dn.w + 1e-6f));
    *reinterpret_cast<float4*>(hhat + (size_t)n * 64 + dc) = o;
  }
}

// ---------- h += relu(BN(hhat)); coef computed inline from sums ----------
__global__ __launch_bounds__(256) void k_update_h(float* __restrict__ h,
                                                  const float* __restrict__ hhat,
                                                  const float* __restrict__ sums,
                                                  const float* __restrict__ gamma,
                                                  const float* __restrict__ beta, int R) {
  int idx = blockIdx.x * 256 + threadIdx.x;
  if (idx >= R * 16) return;
  int r = idx >> 4, dc = (idx & 15) << 2;
  const float invR = 1.f / (float)R;
  float4 sv = *reinterpret_cast<const float4*>(sums + dc);
  float4 qv = *reinterpret_cast<const float4*>(sums + 64 + dc);
  float4 gm = *reinterpret_cast<const float4*>(gamma + dc);
  float4 bt = *reinterpret_cast<const float4*>(beta + dc);
  float m0 = sv.x * invR, m1 = sv.y * invR, m2 = sv.z * invR, m3 = sv.w * invR;
  float c0 = gm.x * rsqrtf(qv.x * invR - m0 * m0 + 1e-5f);
  float c1 = gm.y * rsqrtf(qv.y * invR - m1 * m1 + 1e-5f);
  float c2 = gm.z * rsqrtf(qv.z * invR - m2 * m2 + 1e-5f);
  float c3 = gm.w * rsqrtf(qv.w * invR - m3 * m3 + 1e-5f);
  float h0 = bt.x - m0 * c0, h1 = bt.y - m1 * c1, h2 = bt.z - m2 * c2, h3 = bt.w - m3 * c3;
  size_t off = (size_t)r * 64 + dc;
  float4 y = *reinterpret_cast<const float4*>(hhat + off);
  float4 x = *reinterpret_cast<const float4*>(h + off);
  x.x += fmaxf(fmaf(c0, y.x, h0), 0.f);
  x.y += fmaxf(fmaf(c1, y.y, h1), 0.f);
  x.z += fmaxf(fmaf(c2, y.z, h2), 0.f);
  x.w += fmaxf(fmaf(c3, y.w, h3), 0.f);
  *reinterpret_cast<float4*>(h + off) = x;
}

// ---------- persistent decoder MFMA, fused layer-3 e-update, permuted scatter-out ----------
__global__ __launch_bounds__(256) void k_decoder_mfma(const float* __restrict__ h,
                                                      const float* __restrict__ e,
                                                      const unsigned short* __restrict__ ehat3,
                                                      const float* __restrict__ sums_e3,
                                                      const float* __restrict__ ge3,
                                                      const float* __restrict__ be3,
                                                      const int* __restrict__ psrc,
                                                      const int* __restrict__ pdst,
                                                      const int* __restrict__ order,
                                                      const float* __restrict__ W1,
                                                      const float* __restrict__ b1,
                                                      const float* __restrict__ W2,
                                                      const float* __restrict__ b2,
                                                      float* __restrict__ out, int E) {
  __shared__ unsigned short Wt[64 * 200];
  __shared__ float s_coef[128];
  const int tid = threadIdx.x;
  if (tid < 64) {
    float mean = sums_e3[tid] / (float)E;
    float var = sums_e3[64 + tid] / (float)E - mean * mean;
    float sc = ge3[tid] * rsqrtf(var + 1e-5f);
    s_coef[tid] = sc;
    s_coef[64 + tid] = be3[tid] - mean * sc;
  }
  for (int i = tid; i < 64 * 192; i += 256) {
    int n = i & 63, k = i >> 6;
    Wt[n * 200 + k] = f2bf(W1[k * 64 + n]);
  }
  __syncthreads();
  const int wid = tid >> 6, lane = tid & 63;
  const int col = lane & 15, g = lane >> 4;
  float b1v[4], w2v[4];
#pragma unroll
  for (int nt = 0; nt < 4; ++nt) { b1v[nt] = b1[nt * 16 + col]; w2v[nt] = W2[nt * 16 + col]; }
  const float bb2 = b2[0];
  const int ntiles = (E + 15) / 16;
  for (int tw = blockIdx.x * 4 + wid; tw < ntiles; tw += gridDim.x * 4) {
    const int eb = tw * 16;
    int p = eb + col;
    if (p >= E) p = E - 1;
    const int se = psrc[p], de = pdst[p];
    f32x4 acc[4] = {};
#pragma unroll
    for (int ks = 0; ks < 6; ++ks) {
      float4 a0, a1;
      if (ks < 4) {
        const float* ap = (ks < 2 ? h + (size_t)se * 64 : h + (size_t)de * 64) + (ks & 1) * 32 + g * 8;
        a0 = *reinterpret_cast<const float4*>(ap);
        a1 = *reinterpret_cast<const float4*>(ap + 4);
      } else {
        const int c0 = (ks - 4) * 32 + g * 8;
        const float* ep = e + (size_t)p * 64 + c0;
        a0 = *reinterpret_cast<const float4*>(ep);
        a1 = *reinterpret_cast<const float4*>(ep + 4);
        uint4 hv = *reinterpret_cast<const uint4*>(ehat3 + (size_t)p * 64 + c0);
        float4 sc0 = *reinterpret_cast<const float4*>(&s_coef[c0]);
        float4 sc1 = *reinterpret_cast<const float4*>(&s_coef[c0 + 4]);
        float4 sh0 = *reinterpret_cast<const float4*>(&s_coef[64 + c0]);
        float4 sh1 = *reinterpret_cast<const float4*>(&s_coef[64 + c0 + 4]);
        a0.x += fmaxf(fmaf(sc0.x, bfl(hv.x), sh0.x), 0.f);
        a0.y += fmaxf(fmaf(sc0.y, bfh(hv.x), sh0.y), 0.f);
        a0.z += fmaxf(fmaf(sc0.z, bfl(hv.y), sh0.z), 0.f);
        a0.w += fmaxf(fmaf(sc0.w, bfh(hv.y), sh0.w), 0.f);
        a1.x += fmaxf(fmaf(sc1.x, bfl(hv.z), sh1.x), 0.f);
        a1.y += fmaxf(fmaf(sc1.y, bfh(hv.z), sh1.y), 0.f);
        a1.z += fmaxf(fmaf(sc1.z, bfl(hv.w), sh1.z), 0.f);
        a1.w += fmaxf(fmaf(sc1.w, bfh(hv.w), sh1.w), 0.f);
      }
      short8 af = pack_bf16x8(a0, a1);
#pragma unroll
      for (int nt = 0; nt < 4; ++nt) {
        short8 bb = lds_frag(&Wt[(nt * 16 + col) * 200 + ks * 32 + g * 8]);
        acc[nt] = __builtin_amdgcn_mfma_f32_16x16x32_bf16(af, bb, acc[nt], 0, 0, 0);
      }
    }
    float pr[4];
#pragma unroll
    for (int r = 0; r < 4; ++r) {
      float s = 0.f;
#pragma unroll
      for (int nt = 0; nt < 4; ++nt)
        s = fmaf(fmaxf(acc[nt][r] + b1v[nt], 0.f), w2v[nt], s);
      pr[r] = s;
    }
#pragma unroll
    for (int off = 1; off <= 8; off <<= 1)
#pragma unroll
      for (int r = 0; r < 4; ++r)
        pr[r] += __shfl_xor(pr[r], off, 64);
    if (col == 0) {
#pragma unroll
      for (int r = 0; r < 4; ++r) {
        int m = eb + g * 4 + r;
        if (m < E) out[order[m]] = pr[r] + bb2;
      }
    }
  }
}

extern "C" void kernel_launch(void* const* d_in, const int* in_sizes, int n_in,
                              void* d_out, int out_size, void* d_ws, size_t ws_size,
                              hipStream_t stream) {
  const float* reads  = (const float*)d_in[0];
  const int*   src    = (const int*)d_in[1];
  const int*   dst    = (const int*)d_in[2];
  const float* sim    = (const float*)d_in[3];
  const float* olen   = (const float*)d_in[4];
  const float* conv_w = (const float*)d_in[5];
  const float* conv_b = (const float*)d_in[6];
  const float* We     = (const float*)d_in[7];
  const float* be     = (const float*)d_in[8];
  const float* A1     = (const float*)d_in[9];
  const float* A2     = (const float*)d_in[10];
  const float* A3     = (const float*)d_in[11];
  const float* bA1    = (const float*)d_in[12];
  const float* bA2    = (const float*)d_in[13];
  const float* bA3    = (const float*)d_in[14];
  const float* U      = (const float*)d_in[15];
  const float* V      = (const float*)d_in[16];
  const float* bU     = (const float*)d_in[17];
  const float* bV     = (const float*)d_in[18];
  const float* bnhg   = (const float*)d_in[19];
  const float* bnhb   = (const float*)d_in[20];
  const float* bneg   = (const float*)d_in[21];
  const float* bneb   = (const float*)d_in[22];
  const float* W1     = (const float*)d_in[23];
  const float* b1     = (const float*)d_in[24];
  const float* W2     = (const float*)d_in[25];
  const float* b2     = (const float*)d_in[26];

  const int N = in_sizes[0] / 512;
  const int E = in_sizes[1];

  // ---- workspace layout: floats, then ushorts, then ints ----
  float* fp = (float*)d_ws;
  float* e    = fp; fp += (size_t)E * 64;
  float* h    = fp; fp += (size_t)N * 64;
  float* hhat = fp; fp += (size_t)N * 64;
  float* numb = fp; fp += (size_t)N * 64;
  float* denb = fp; fp += (size_t)N * 64;
  float* sums = fp; fp += 1024;  // 4 layers x 128 (e) then 4 x 128 (h)
  unsigned short* up = (unsigned short*)fp;
  unsigned short* ehatA = up; up += (size_t)E * 64;
  unsigned short* ehatB = up; up += (size_t)E * 64;
  unsigned short* XA1 = up; up += (size_t)N * 64;
  unsigned short* XA2 = up; up += (size_t)N * 64;
  unsigned short* XV  = up; up += (size_t)N * 64;
  int* ip = (int*)up;
  int* order   = ip; ip += E;
  int* psrc    = ip; ip += E;
  int* pdst    = ip; ip += E;
  int* cnt     = ip; ip += N;
  int* nxt     = ip; ip += N;
  int* row_ptr = ip; ip += N + 1;
  float* out = (float*)d_out;

  hipMemsetAsync(cnt, 0, sizeof(int) * N, stream);
  hipMemsetAsync(sums, 0, sizeof(float) * 1024, stream);
  k_hist<<<(E + 255) / 256, 256, 0, stream>>>(dst, cnt, E);
  k_scan<<<1, 1024, 0, stream>>>(cnt, row_ptr, nxt, N, E);
  k_scatter<<<(E + 255) / 256, 256, 0, stream>>>(dst, src, nxt, order, psrc, pdst, E);

  k_conv_mfma<<<(N + 3) / 4, 256, 0, stream>>>(reads, conv_w, conv_b, h, N);
  k_edge_enc<<<(E * 16 + 255) / 256, 256, 0, stream>>>(sim, olen, order, We, be, e, E);

  const int PBLK = 1024;
  unsigned short* ehat_cur = ehatA;
  unsigned short* ehat_prev = ehatB;
  for (int l = 0; l < 4; ++l) {
    ehat_cur = (l & 1) ? ehatB : ehatA;
    ehat_prev = (l & 1) ? ehatA : ehatB;
    float* sums_e = sums + l * 128;
    float* sums_h = sums + 512 + l * 128;
    const float* sums_e_prev = sums + (l - 1) * 128;
    k_node_gemm<<<dim3((N + 255) / 256, 3), 256, 0, stream>>>(
        h, A1 + l * 4096, A2 + l * 4096, V + l * 4096,
        bA1 + l * 64, bA2 + l * 64, bV + l * 64, XA1, XA2, XV, N);
    k_edge_mfma<<<PBLK, 256, 0, stream>>>(
        e, ehat_prev, ehat_cur,
        l > 0 ? sums_e_prev : sums, bneg + (l > 0 ? (l - 1) * 64 : 0),
        bneb + (l > 0 ? (l - 1) * 64 : 0),
        psrc, pdst, XA1, XA2, A3 + l * 4096, bA3 + l * 64, E, l > 0 ? 1 : 0);
    k_stats_bf16<<<1024, 256, 0, stream>>>(ehat_cur, E, sums_e);
    k_aggregate<<<(N * 16 + 255) / 256, 256, 0, stream>>>(
        row_ptr, psrc, ehat_cur, XV, numb, denb, N);
    k_hhat<<<(N + 255) / 256, 256, 0, stream>>>(
        h, U + l * 4096, bU + l * 64, numb, denb, hhat, N);
    k_stats<<<256, 256, 0, stream>>>(hhat, N, sums_h);
    k_update_h<<<(N * 16 + 255) / 256, 256, 0, stream>>>(
        h, hhat, sums_h, bnhg + l * 64, bnhb + l * 64, N);
  }

  k_decoder_mfma<<<PBLK, 256, 0, stream>>>(
      h, e, ehat_cur, sums + 3 * 128, bneg + 3 * 64, bneb + 3 * 64,
      psrc, pdst, order, W1, b1, W2, b2, out, E);
}

// Round 6
// 1233.307 us; speedup vs baseline: 1.3233x; 1.3233x over previous
//
#include <hip/hip_runtime.h>
#include <hip/hip_bf16.h>
#include <cstdint>
#include <cstddef>

#define DD 64

typedef __attribute__((ext_vector_type(8))) short short8;
typedef __attribute__((ext_vector_type(4))) float f32x4;

__device__ __forceinline__ float4 f4_0() { return make_float4(0.f, 0.f, 0.f, 0.f); }

__device__ __forceinline__ unsigned short f2bf(float f) {
  __hip_bfloat16 h = __float2bfloat16(f);
  return *reinterpret_cast<unsigned short*>(&h);
}
__device__ __forceinline__ float bfl(unsigned u) { return __uint_as_float(u << 16); }
__device__ __forceinline__ float bfh(unsigned u) { return __uint_as_float(u & 0xffff0000u); }
__device__ __forceinline__ float b2f(unsigned short u) {
  return __uint_as_float(((unsigned)u) << 16);
}

__device__ __forceinline__ short8 pack_bf16x8(float4 a, float4 b) {
  union { unsigned short us[8]; short8 v; } pk;
  pk.us[0] = f2bf(a.x); pk.us[1] = f2bf(a.y); pk.us[2] = f2bf(a.z); pk.us[3] = f2bf(a.w);
  pk.us[4] = f2bf(b.x); pk.us[5] = f2bf(b.y); pk.us[6] = f2bf(b.z); pk.us[7] = f2bf(b.w);
  return pk.v;
}

__device__ __forceinline__ short8 lds_frag(const unsigned short* p) {
  uint2 lo = *reinterpret_cast<const uint2*>(p);
  uint2 hi = *reinterpret_cast<const uint2*>(p + 4);
  union { unsigned u[4]; short8 v; } t;
  t.u[0] = lo.x; t.u[1] = lo.y; t.u[2] = hi.x; t.u[3] = hi.y;
  return t.v;
}

// ---------- row GEMM (fp32, node-side) ----------
__device__ __forceinline__ void row_gemm64(const float* __restrict__ row,
                                           const float* __restrict__ W,
                                           float acc[DD]) {
  for (int k4 = 0; k4 < DD; k4 += 4) {
    const float4 rv = *reinterpret_cast<const float4*>(row + k4);
    const float rvals[4] = {rv.x, rv.y, rv.z, rv.w};
#pragma unroll
    for (int kk = 0; kk < 4; ++kk) {
      const float v = rvals[kk];
      const float* wr = W + (k4 + kk) * DD;
#pragma unroll
      for (int d = 0; d < DD; ++d) acc[d] = fmaf(v, wr[d], acc[d]);
    }
  }
}

__device__ __forceinline__ void init_bias64(const float* __restrict__ b, float acc[DD]) {
#pragma unroll
  for (int d = 0; d < DD; ++d) acc[d] = b[d];
}

// ---------- CSR build ----------
__global__ __launch_bounds__(256) void k_hist(const int* __restrict__ dst,
                                              int* __restrict__ cnt, int E) {
  int j = blockIdx.x * 256 + threadIdx.x;
  if (j < E) atomicAdd(&cnt[dst[j]], 1);
}

__global__ __launch_bounds__(1024) void k_scan(const int* __restrict__ cnt,
                                               int* __restrict__ row_ptr,
                                               int* __restrict__ nxt, int N, int E) {
  __shared__ int wsum[16];
  __shared__ int carry_s;
  const int tid = threadIdx.x;
  const int wid = tid >> 6, lane = tid & 63;
  if (tid == 0) carry_s = 0;
  __syncthreads();
  const int nt = (N + 1023) / 1024;
  for (int b = 0; b < nt; ++b) {
    int i = b * 1024 + tid;
    int v = (i < N) ? cnt[i] : 0;
    int x = v;
#pragma unroll
    for (int off = 1; off < 64; off <<= 1) {
      int y = __shfl_up(x, off, 64);
      if (lane >= off) x += y;
    }
    if (lane == 63) wsum[wid] = x;
    __syncthreads();
    if (wid == 0 && lane < 16) {
      int wv = wsum[lane];
#pragma unroll
      for (int off = 1; off < 16; off <<= 1) {
        int y = __shfl_up(wv, off, 64);
        if (lane >= off) wv += y;
      }
      wsum[lane] = wv;
    }
    __syncthreads();
    int base = carry_s + (wid > 0 ? wsum[wid - 1] : 0);
    int excl = base + x - v;
    if (i < N) { row_ptr[i] = excl; nxt[i] = excl; }
    __syncthreads();
    if (tid == 0) carry_s += wsum[15];
    __syncthreads();
  }
  if (tid == 0) row_ptr[N] = E;
}

__global__ __launch_bounds__(256) void k_scatter(const int* __restrict__ dst,
                                                 const int* __restrict__ src,
                                                 int* __restrict__ nxt,
                                                 int* __restrict__ order,
                                                 int* __restrict__ psrc,
                                                 int* __restrict__ pdst, int E) {
  int j = blockIdx.x * 256 + threadIdx.x;
  if (j >= E) return;
  int d = dst[j];
  int pos = atomicAdd(&nxt[d], 1);
  order[pos] = j;
  psrc[pos] = src[j];
  pdst[pos] = d;
}

// ---------- conv1d + maxpool via bf16 MFMA ----------
// Staging now uses v_cvt_pk_bf16_f32 + v_alignbit to build the 4 shift-copies
// directly in packed dwords (was: 8 scalar converts + manual packing).
__global__ __launch_bounds__(256) void k_conv_mfma(const float* __restrict__ reads,
                                                   const float* __restrict__ w,
                                                   const float* __restrict__ bias,
                                                   float* __restrict__ h, int N) {
  __shared__ unsigned short cp[4 * 4 * 4 * 144];  // [node][c][s][144]
  const int tid = threadIdx.x;
  const int nb = blockIdx.x * 4;
  for (int task = tid; task < 576; task += 256) {
    const int node = task / 144;
    const int rem = task % 144;
    const int c = rem / 36;
    const int u = rem % 36;
    const int gn = nb + node;
    float4 v0 = f4_0(), v1 = f4_0();
    if (gn < N) {
      const float* rp = reads + (size_t)gn * 512 + c * 128 + 4 * u;
      if (u <= 31) v0 = *reinterpret_cast<const float4*>(rp);
      if (u <= 30) v1 = *reinterpret_cast<const float4*>(rp + 4);
    }
    unsigned pk0, pk1, pk2, pk3;
    asm("v_cvt_pk_bf16_f32 %0, %1, %2" : "=v"(pk0) : "v"(v0.x), "v"(v0.y));
    asm("v_cvt_pk_bf16_f32 %0, %1, %2" : "=v"(pk1) : "v"(v0.z), "v"(v0.w));
    asm("v_cvt_pk_bf16_f32 %0, %1, %2" : "=v"(pk2) : "v"(v1.x), "v"(v1.y));
    asm("v_cvt_pk_bf16_f32 %0, %1, %2" : "=v"(pk3) : "v"(v1.z), "v"(v1.w));
    const unsigned a0 = __builtin_amdgcn_alignbit(pk1, pk0, 16);  // e1|e2<<16
    const unsigned a1 = __builtin_amdgcn_alignbit(pk2, pk1, 16);  // e3|e4<<16
    const unsigned a2 = __builtin_amdgcn_alignbit(pk3, pk2, 16);  // e5|e6<<16
    const int base = ((node * 4 + c) * 4) * 144 + 4 * u;
    *reinterpret_cast<uint2*>(&cp[base + 0 * 144]) = make_uint2(pk0, pk1);
    *reinterpret_cast<uint2*>(&cp[base + 1 * 144]) = make_uint2(a0, a1);
    *reinterpret_cast<uint2*>(&cp[base + 2 * 144]) = make_uint2(pk1, pk2);
    *reinterpret_cast<uint2*>(&cp[base + 3 * 144]) = make_uint2(a1, a2);
  }
  __syncthreads();
  const int wid = tid >> 6, lane = tid & 63;
  const int gn = nb + wid;
  if (gn >= N) return;
  const int col = lane & 15, grp = lane >> 4;
  short8 af[4][2];
#pragma unroll
  for (int mt = 0; mt < 4; ++mt)
#pragma unroll
    for (int ks = 0; ks < 2; ++ks) {
      const int d = col + 16 * mt;
      const int kb = ks * 32 + grp * 8;
      const float* wp = w + d * 64 + kb;
      float4 w0 = *reinterpret_cast<const float4*>(wp);
      float4 w1 = *reinterpret_cast<const float4*>(wp + 4);
      af[mt][ks] = pack_bf16x8(w0, w1);
    }
  float vmax[4][4];
#pragma unroll
  for (int mt = 0; mt < 4; ++mt)
#pragma unroll
    for (int r = 0; r < 4; ++r) vmax[mt][r] = -3.0e38f;
  const int s = col & 3;
  for (int ntile = 0; ntile < 8; ++ntile) {
    const int t = ntile * 16 + col;
    f32x4 acc[4] = {};
#pragma unroll
    for (int ks = 0; ks < 2; ++ks) {
      const int kbase = ks * 32 + grp * 8;
      const int c = kbase >> 4;
      const int kk0 = kbase & 15;
      const int q = (t - s) + kk0;
      const unsigned short* p = &cp[((wid * 4 + c) * 4 + s) * 144 + q];
      short8 bb = lds_frag(p);
#pragma unroll
      for (int mt = 0; mt < 4; ++mt)
        acc[mt] = __builtin_amdgcn_mfma_f32_16x16x32_bf16(af[mt][ks], bb, acc[mt], 0, 0, 0);
    }
    if (t < 113) {
#pragma unroll
      for (int mt = 0; mt < 4; ++mt)
#pragma unroll
        for (int r = 0; r < 4; ++r) vmax[mt][r] = fmaxf(vmax[mt][r], acc[mt][r]);
    }
  }
#pragma unroll
  for (int off = 8; off >= 1; off >>= 1)
#pragma unroll
    for (int mt = 0; mt < 4; ++mt)
#pragma unroll
      for (int r = 0; r < 4; ++r)
        vmax[mt][r] = fmaxf(vmax[mt][r], __shfl_xor(vmax[mt][r], off, 64));
  if (col == 0) {
#pragma unroll
    for (int mt = 0; mt < 4; ++mt)
#pragma unroll
      for (int r = 0; r < 4; ++r) {
        const int d = mt * 16 + grp * 4 + r;
        h[(size_t)gn * 64 + d] = vmax[mt][r] + bias[d];
      }
  }
}

// ---------- edge encoder (writes e in PERMUTED layout) ----------
__global__ __launch_bounds__(256) void k_edge_enc(const float* __restrict__ sim,
                                                  const float* __restrict__ len,
                                                  const int* __restrict__ order,
                                                  const float* __restrict__ We,
                                                  const float* __restrict__ be,
                                                  float* __restrict__ e, int E) {
  int idx = blockIdx.x * 256 + threadIdx.x;
  if (idx >= E * 16) return;
  int j = idx >> 4, dc = (idx & 15) << 2;
  int oj = order[j];
  float s = sim[oj], L = len[oj];
  float4 w0 = *reinterpret_cast<const float4*>(We + dc);
  float4 w1 = *reinterpret_cast<const float4*>(We + 64 + dc);
  float4 b  = *reinterpret_cast<const float4*>(be + dc);
  float4 o;
  o.x = fmaf(s, w0.x, fmaf(L, w1.x, b.x));
  o.y = fmaf(s, w0.y, fmaf(L, w1.y, b.y));
  o.z = fmaf(s, w0.z, fmaf(L, w1.z, b.z));
  o.w = fmaf(s, w0.w, fmaf(L, w1.w, b.w));
  *reinterpret_cast<float4*>(e + (size_t)j * 64 + dc) = o;
}

// ---------- node GEMMs (fp32 compute, bf16 output) ----------
__global__ __launch_bounds__(256) void k_node_gemm(const float* __restrict__ h,
                                                   const float* __restrict__ Wa,
                                                   const float* __restrict__ Wb,
                                                   const float* __restrict__ Wc,
                                                   const float* __restrict__ ba,
                                                   const float* __restrict__ bb,
                                                   const float* __restrict__ bc,
                                                   unsigned short* __restrict__ Xa,
                                                   unsigned short* __restrict__ Xb,
                                                   unsigned short* __restrict__ Xc, int N) {
  const float* W; const float* bi; unsigned short* X;
  if (blockIdx.y == 0)      { W = Wa; bi = ba; X = Xa; }
  else if (blockIdx.y == 1) { W = Wb; bi = bb; X = Xb; }
  else                      { W = Wc; bi = bc; X = Xc; }
  int n = blockIdx.x * 256 + threadIdx.x;
  if (n >= N) return;
  float acc[DD];
  init_bias64(bi, acc);
  row_gemm64(h + (size_t)n * 64, W, acc);
#pragma unroll
  for (int d8 = 0; d8 < DD; d8 += 8) {
    uint4 pk;
    pk.x = (unsigned)f2bf(acc[d8 + 0]) | ((unsigned)f2bf(acc[d8 + 1]) << 16);
    pk.y = (unsigned)f2bf(acc[d8 + 2]) | ((unsigned)f2bf(acc[d8 + 3]) << 16);
    pk.z = (unsigned)f2bf(acc[d8 + 4]) | ((unsigned)f2bf(acc[d8 + 5]) << 16);
    pk.w = (unsigned)f2bf(acc[d8 + 6]) | ((unsigned)f2bf(acc[d8 + 7]) << 16);
    *reinterpret_cast<uint4*>(X + (size_t)n * 64 + d8) = pk;
  }
}

// ---------- persistent edge MFMA, fused prev-layer e-update + fused BN stats ----------
__global__ __launch_bounds__(256) void k_edge_mfma(float* __restrict__ e,
                                                   const unsigned short* __restrict__ ehat_prev,
                                                   unsigned short* __restrict__ ehat_out,
                                                   const float* __restrict__ sums_prev,
                                                   const float* __restrict__ gprev,
                                                   const float* __restrict__ bprev,
                                                   const int* __restrict__ psrc,
                                                   const int* __restrict__ pdst,
                                                   const unsigned short* __restrict__ XA1,
                                                   const unsigned short* __restrict__ XA2,
                                                   const float* __restrict__ A3,
                                                   const float* __restrict__ bA3,
                                                   float* __restrict__ sums_out,
                                                   int E, int hasupd) {
  __shared__ unsigned short At[64 * 72];
  __shared__ float s_coef[128];
  __shared__ float s_sums[128];
  const int tid = threadIdx.x;
  if (tid < 128) s_sums[tid] = 0.f;
  if (hasupd && tid < 64) {
    float mean = sums_prev[tid] / (float)E;
    float var = sums_prev[64 + tid] / (float)E - mean * mean;
    float sc = gprev[tid] * rsqrtf(var + 1e-5f);
    s_coef[tid] = sc;
    s_coef[64 + tid] = bprev[tid] - mean * sc;
  }
  for (int i = tid; i < 4096; i += 256) {
    int n = i & 63, k = i >> 6;
    At[n * 72 + k] = f2bf(A3[k * 64 + n]);
  }
  __syncthreads();
  const int wid = tid >> 6, lane = tid & 63;
  const int col = lane & 15, g = lane >> 4;
  short8 aa[4][2];
#pragma unroll
  for (int mt = 0; mt < 4; ++mt)
#pragma unroll
    for (int ks = 0; ks < 2; ++ks)
      aa[mt][ks] = lds_frag(&At[(mt * 16 + col) * 72 + ks * 32 + g * 8]);
  float4 ba[4];
#pragma unroll
  for (int mt = 0; mt < 4; ++mt)
    ba[mt] = *reinterpret_cast<const float4*>(bA3 + mt * 16 + g * 4);
  float statS[16], statQ[16];
#pragma unroll
  for (int i = 0; i < 16; ++i) { statS[i] = 0.f; statQ[i] = 0.f; }
  const int ntiles = (E + 15) / 16;
  for (int tw = blockIdx.x * 4 + wid; tw < ntiles; tw += gridDim.x * 4) {
    int p = tw * 16 + col;
    const bool valid = p < E;
    if (!valid) p = E - 1;
    const int se = psrc[p], de = pdst[p];
    short8 bfr[2];
#pragma unroll
    for (int ks = 0; ks < 2; ++ks) {
      float* ep = e + (size_t)p * 64 + ks * 32 + g * 8;
      float4 e0 = *reinterpret_cast<const float4*>(ep);
      float4 e1 = *reinterpret_cast<const float4*>(ep + 4);
      if (hasupd) {
        const int c0 = ks * 32 + g * 8;
        uint4 hv = *reinterpret_cast<const uint4*>(ehat_prev + (size_t)p * 64 + c0);
        float4 sc0 = *reinterpret_cast<const float4*>(&s_coef[c0]);
        float4 sc1 = *reinterpret_cast<const float4*>(&s_coef[c0 + 4]);
        float4 sh0 = *reinterpret_cast<const float4*>(&s_coef[64 + c0]);
        float4 sh1 = *reinterpret_cast<const float4*>(&s_coef[64 + c0 + 4]);
        e0.x += fmaxf(fmaf(sc0.x, bfl(hv.x), sh0.x), 0.f);
        e0.y += fmaxf(fmaf(sc0.y, bfh(hv.x), sh0.y), 0.f);
        e0.z += fmaxf(fmaf(sc0.z, bfl(hv.y), sh0.z), 0.f);
        e0.w += fmaxf(fmaf(sc0.w, bfh(hv.y), sh0.w), 0.f);
        e1.x += fmaxf(fmaf(sc1.x, bfl(hv.z), sh1.x), 0.f);
        e1.y += fmaxf(fmaf(sc1.y, bfh(hv.z), sh1.y), 0.f);
        e1.z += fmaxf(fmaf(sc1.z, bfl(hv.w), sh1.z), 0.f);
        e1.w += fmaxf(fmaf(sc1.w, bfh(hv.w), sh1.w), 0.f);
        if (valid) {
          *reinterpret_cast<float4*>(ep) = e0;
          *reinterpret_cast<float4*>(ep + 4) = e1;
        }
      }
      bfr[ks] = pack_bf16x8(e0, e1);
    }
    f32x4 acc[4] = {};
#pragma unroll
    for (int ks = 0; ks < 2; ++ks)
#pragma unroll
      for (int mt = 0; mt < 4; ++mt)
        acc[mt] = __builtin_amdgcn_mfma_f32_16x16x32_bf16(aa[mt][ks], bfr[ks], acc[mt], 0, 0, 0);
    if (valid) {
#pragma unroll
      for (int mt = 0; mt < 4; ++mt) {
        const int chb = mt * 16 + g * 4;
        ushort4 x1 = *reinterpret_cast<const ushort4*>(XA1 + (size_t)se * 64 + chb);
        ushort4 x2 = *reinterpret_cast<const ushort4*>(XA2 + (size_t)de * 64 + chb);
        float o0 = acc[mt][0] + b2f(x1.x) + b2f(x2.x) + ba[mt].x;
        float o1 = acc[mt][1] + b2f(x1.y) + b2f(x2.y) + ba[mt].y;
        float o2 = acc[mt][2] + b2f(x1.z) + b2f(x2.z) + ba[mt].z;
        float o3 = acc[mt][3] + b2f(x1.w) + b2f(x2.w) + ba[mt].w;
        ushort4 ov;
        ov.x = f2bf(o0); ov.y = f2bf(o1); ov.z = f2bf(o2); ov.w = f2bf(o3);
        *reinterpret_cast<ushort4*>(ehat_out + (size_t)p * 64 + chb) = ov;
        statS[mt * 4 + 0] += o0; statQ[mt * 4 + 0] = fmaf(o0, o0, statQ[mt * 4 + 0]);
        statS[mt * 4 + 1] += o1; statQ[mt * 4 + 1] = fmaf(o1, o1, statQ[mt * 4 + 1]);
        statS[mt * 4 + 2] += o2; statQ[mt * 4 + 2] = fmaf(o2, o2, statQ[mt * 4 + 2]);
        statS[mt * 4 + 3] += o3; statQ[mt * 4 + 3] = fmaf(o3, o3, statQ[mt * 4 + 3]);
      }
    }
  }
  // single end-of-kernel reduction across the 16 col-lanes of each g-group
#pragma unroll
  for (int off = 1; off <= 8; off <<= 1)
#pragma unroll
    for (int i = 0; i < 16; ++i) {
      statS[i] += __shfl_xor(statS[i], off, 64);
      statQ[i] += __shfl_xor(statQ[i], off, 64);
    }
  if (col == 0) {
#pragma unroll
    for (int mt = 0; mt < 4; ++mt)
#pragma unroll
      for (int c = 0; c < 4; ++c) {
        const int ch = mt * 16 + g * 4 + c;
        atomicAdd(&s_sums[ch], statS[mt * 4 + c]);
        atomicAdd(&s_sums[64 + ch], statQ[mt * 4 + c]);
      }
  }
  __syncthreads();
  if (tid < 128) atomicAdd(&sums_out[tid], s_sums[tid]);
}

// ---------- per-channel stats over fp32 rows (hhat) ----------
__global__ __launch_bounds__(256) void k_stats(const float* __restrict__ X, int R,
                                               float* __restrict__ sums) {
  __shared__ float red[2][16][64];
  int tid = threadIdx.x;
  int g = tid >> 4, dc = (tid & 15) << 2;
  float4 s = f4_0(), q = f4_0();
  for (int r = blockIdx.x * 16 + g; r < R; r += gridDim.x * 16) {
    float4 v = *reinterpret_cast<const float4*>(X + (size_t)r * 64 + dc);
    s.x += v.x; s.y += v.y; s.z += v.z; s.w += v.w;
    q.x = fmaf(v.x, v.x, q.x); q.y = fmaf(v.y, v.y, q.y);
    q.z = fmaf(v.z, v.z, q.z); q.w = fmaf(v.w, v.w, q.w);
  }
  *reinterpret_cast<float4*>(&red[0][g][dc]) = s;
  *reinterpret_cast<float4*>(&red[1][g][dc]) = q;
  __syncthreads();
  if (g == 0) {
    float4 ts = f4_0(), tq = f4_0();
#pragma unroll
    for (int gg = 0; gg < 16; ++gg) {
      float4 a = *reinterpret_cast<const float4*>(&red[0][gg][dc]);
      float4 b = *reinterpret_cast<const float4*>(&red[1][gg][dc]);
      ts.x += a.x; ts.y += a.y; ts.z += a.z; ts.w += a.w;
      tq.x += b.x; tq.y += b.y; tq.z += b.z; tq.w += b.w;
    }
    atomicAdd(&sums[dc], ts.x); atomicAdd(&sums[dc + 1], ts.y);
    atomicAdd(&sums[dc + 2], ts.z); atomicAdd(&sums[dc + 3], ts.w);
    atomicAdd(&sums[64 + dc], tq.x); atomicAdd(&sums[64 + dc + 1], tq.y);
    atomicAdd(&sums[64 + dc + 2], tq.z); atomicAdd(&sums[64 + dc + 3], tq.w);
  }
}

// ---------- aggregation (sequential CSR rows) ----------
__global__ __launch_bounds__(256) void k_aggregate(const int* __restrict__ row_ptr,
                                                   const int* __restrict__ psrc,
                                                   const unsigned short* __restrict__ ehat,
                                                   const unsigned short* __restrict__ XV,
                                                   float* __restrict__ num,
                                                   float* __restrict__ den, int N) {
  int idx = blockIdx.x * 256 + threadIdx.x;
  if (idx >= N * 16) return;
  int n = idx >> 4, dc = (idx & 15) << 2;
  int beg = row_ptr[n], end = row_ptr[n + 1];
  float4 nm = f4_0(), dn = f4_0();
  for (int i = beg; i < end; ++i) {
    int sj = psrc[i];
    uint2 ev = *reinterpret_cast<const uint2*>(ehat + (size_t)i * 64 + dc);
    uint2 vv = *reinterpret_cast<const uint2*>(XV + (size_t)sj * 64 + dc);
    float s0 = 1.f / (1.f + __expf(-bfl(ev.x)));
    float s1 = 1.f / (1.f + __expf(-bfh(ev.x)));
    float s2 = 1.f / (1.f + __expf(-bfl(ev.y)));
    float s3 = 1.f / (1.f + __expf(-bfh(ev.y)));
    dn.x += s0; dn.y += s1; dn.z += s2; dn.w += s3;
    nm.x = fmaf(s0, bfl(vv.x), nm.x);
    nm.y = fmaf(s1, bfh(vv.x), nm.y);
    nm.z = fmaf(s2, bfl(vv.y), nm.z);
    nm.w = fmaf(s3, bfh(vv.y), nm.w);
  }
  *reinterpret_cast<float4*>(num + (size_t)n * 64 + dc) = nm;
  *reinterpret_cast<float4*>(den + (size_t)n * 64 + dc) = dn;
}

// ---------- h_hat (fp32) ----------
__global__ __launch_bounds__(256) void k_hhat(const float* __restrict__ h,
                                              const float* __restrict__ Uw,
                                              const float* __restrict__ bU,
                                              const float* __restrict__ num,
                                              const float* __restrict__ den,
                                              float* __restrict__ hhat, int N) {
  int n = blockIdx.x * 256 + threadIdx.x;
  if (n >= N) return;
  float acc[DD];
  init_bias64(bU, acc);
  row_gemm64(h + (size_t)n * 64, Uw, acc);
#pragma unroll
  for (int dc = 0; dc < DD; dc += 4) {
    float4 nm = *reinterpret_cast<const float4*>(num + (size_t)n * 64 + dc);
    float4 dn = *reinterpret_cast<const float4*>(den + (size_t)n * 64 + dc);
    float4 o = make_float4(acc[dc] + nm.x / (dn.x + 1e-6f),
                           acc[dc + 1] + nm.y / (dn.y + 1e-6f),
                           acc[dc + 2] + nm.z / (dn.z + 1e-6f),
                           acc[dc + 3] + nm.w / (dn.w + 1e-6f));
    *reinterpret_cast<float4*>(hhat + (size_t)n * 64 + dc) = o;
  }
}

// ---------- h += relu(BN(hhat)); coef computed inline from sums ----------
__global__ __launch_bounds__(256) void k_update_h(float* __restrict__ h,
                                                  const float* __restrict__ hhat,
                                                  const float* __restrict__ sums,
                                                  const float* __restrict__ gamma,
                                                  const float* __restrict__ beta, int R) {
  int idx = blockIdx.x * 256 + threadIdx.x;
  if (idx >= R * 16) return;
  int r = idx >> 4, dc = (idx & 15) << 2;
  const float invR = 1.f / (float)R;
  float4 sv = *reinterpret_cast<const float4*>(sums + dc);
  float4 qv = *reinterpret_cast<const float4*>(sums + 64 + dc);
  float4 gm = *reinterpret_cast<const float4*>(gamma + dc);
  float4 bt = *reinterpret_cast<const float4*>(beta + dc);
  float m0 = sv.x * invR, m1 = sv.y * invR, m2 = sv.z * invR, m3 = sv.w * invR;
  float c0 = gm.x * rsqrtf(qv.x * invR - m0 * m0 + 1e-5f);
  float c1 = gm.y * rsqrtf(qv.y * invR - m1 * m1 + 1e-5f);
  float c2 = gm.z * rsqrtf(qv.z * invR - m2 * m2 + 1e-5f);
  float c3 = gm.w * rsqrtf(qv.w * invR - m3 * m3 + 1e-5f);
  float h0 = bt.x - m0 * c0, h1 = bt.y - m1 * c1, h2 = bt.z - m2 * c2, h3 = bt.w - m3 * c3;
  size_t off = (size_t)r * 64 + dc;
  float4 y = *reinterpret_cast<const float4*>(hhat + off);
  float4 x = *reinterpret_cast<const float4*>(h + off);
  x.x += fmaxf(fmaf(c0, y.x, h0), 0.f);
  x.y += fmaxf(fmaf(c1, y.y, h1), 0.f);
  x.z += fmaxf(fmaf(c2, y.z, h2), 0.f);
  x.w += fmaxf(fmaf(c3, y.w, h3), 0.f);
  *reinterpret_cast<float4*>(h + off) = x;
}

// ---------- persistent decoder MFMA, fused layer-3 e-update, permuted scatter-out ----------
__global__ __launch_bounds__(256) void k_decoder_mfma(const float* __restrict__ h,
                                                      const float* __restrict__ e,
                                                      const unsigned short* __restrict__ ehat3,
                                                      const float* __restrict__ sums_e3,
                                                      const float* __restrict__ ge3,
                                                      const float* __restrict__ be3,
                                                      const int* __restrict__ psrc,
                                                      const int* __restrict__ pdst,
                                                      const int* __restrict__ order,
                                                      const float* __restrict__ W1,
                                                      const float* __restrict__ b1,
                                                      const float* __restrict__ W2,
                                                      const float* __restrict__ b2,
                                                      float* __restrict__ out, int E) {
  __shared__ unsigned short Wt[64 * 200];
  __shared__ float s_coef[128];
  const int tid = threadIdx.x;
  if (tid < 64) {
    float mean = sums_e3[tid] / (float)E;
    float var = sums_e3[64 + tid] / (float)E - mean * mean;
    float sc = ge3[tid] * rsqrtf(var + 1e-5f);
    s_coef[tid] = sc;
    s_coef[64 + tid] = be3[tid] - mean * sc;
  }
  for (int i = tid; i < 64 * 192; i += 256) {
    int n = i & 63, k = i >> 6;
    Wt[n * 200 + k] = f2bf(W1[k * 64 + n]);
  }
  __syncthreads();
  const int wid = tid >> 6, lane = tid & 63;
  const int col = lane & 15, g = lane >> 4;
  float b1v[4], w2v[4];
#pragma unroll
  for (int nt = 0; nt < 4; ++nt) { b1v[nt] = b1[nt * 16 + col]; w2v[nt] = W2[nt * 16 + col]; }
  const float bb2 = b2[0];
  const int ntiles = (E + 15) / 16;
  for (int tw = blockIdx.x * 4 + wid; tw < ntiles; tw += gridDim.x * 4) {
    const int eb = tw * 16;
    int p = eb + col;
    if (p >= E) p = E - 1;
    const int se = psrc[p], de = pdst[p];
    f32x4 acc[4] = {};
#pragma unroll
    for (int ks = 0; ks < 6; ++ks) {
      float4 a0, a1;
      if (ks < 4) {
        const float* ap = (ks < 2 ? h + (size_t)se * 64 : h + (size_t)de * 64) + (ks & 1) * 32 + g * 8;
        a0 = *reinterpret_cast<const float4*>(ap);
        a1 = *reinterpret_cast<const float4*>(ap + 4);
      } else {
        const int c0 = (ks - 4) * 32 + g * 8;
        const float* ep = e + (size_t)p * 64 + c0;
        a0 = *reinterpret_cast<const float4*>(ep);
        a1 = *reinterpret_cast<const float4*>(ep + 4);
        uint4 hv = *reinterpret_cast<const uint4*>(ehat3 + (size_t)p * 64 + c0);
        float4 sc0 = *reinterpret_cast<const float4*>(&s_coef[c0]);
        float4 sc1 = *reinterpret_cast<const float4*>(&s_coef[c0 + 4]);
        float4 sh0 = *reinterpret_cast<const float4*>(&s_coef[64 + c0]);
        float4 sh1 = *reinterpret_cast<const float4*>(&s_coef[64 + c0 + 4]);
        a0.x += fmaxf(fmaf(sc0.x, bfl(hv.x), sh0.x), 0.f);
        a0.y += fmaxf(fmaf(sc0.y, bfh(hv.x), sh0.y), 0.f);
        a0.z += fmaxf(fmaf(sc0.z, bfl(hv.y), sh0.z), 0.f);
        a0.w += fmaxf(fmaf(sc0.w, bfh(hv.y), sh0.w), 0.f);
        a1.x += fmaxf(fmaf(sc1.x, bfl(hv.z), sh1.x), 0.f);
        a1.y += fmaxf(fmaf(sc1.y, bfh(hv.z), sh1.y), 0.f);
        a1.z += fmaxf(fmaf(sc1.z, bfl(hv.w), sh1.z), 0.f);
        a1.w += fmaxf(fmaf(sc1.w, bfh(hv.w), sh1.w), 0.f);
      }
      short8 af = pack_bf16x8(a0, a1);
#pragma unroll
      for (int nt = 0; nt < 4; ++nt) {
        short8 bb = lds_frag(&Wt[(nt * 16 + col) * 200 + ks * 32 + g * 8]);
        acc[nt] = __builtin_amdgcn_mfma_f32_16x16x32_bf16(af, bb, acc[nt], 0, 0, 0);
      }
    }
    float pr[4];
#pragma unroll
    for (int r = 0; r < 4; ++r) {
      float s = 0.f;
#pragma unroll
      for (int nt = 0; nt < 4; ++nt)
        s = fmaf(fmaxf(acc[nt][r] + b1v[nt], 0.f), w2v[nt], s);
      pr[r] = s;
    }
#pragma unroll
    for (int off = 1; off <= 8; off <<= 1)
#pragma unroll
      for (int r = 0; r < 4; ++r)
        pr[r] += __shfl_xor(pr[r], off, 64);
    if (col == 0) {
#pragma unroll
      for (int r = 0; r < 4; ++r) {
        int m = eb + g * 4 + r;
        if (m < E) out[order[m]] = pr[r] + bb2;
      }
    }
  }
}

extern "C" void kernel_launch(void* const* d_in, const int* in_sizes, int n_in,
                              void* d_out, int out_size, void* d_ws, size_t ws_size,
                              hipStream_t stream) {
  const float* reads  = (const float*)d_in[0];
  const int*   src    = (const int*)d_in[1];
  const int*   dst    = (const int*)d_in[2];
  const float* sim    = (const float*)d_in[3];
  const float* olen   = (const float*)d_in[4];
  const float* conv_w = (const float*)d_in[5];
  const float* conv_b = (const float*)d_in[6];
  const float* We     = (const float*)d_in[7];
  const float* be     = (const float*)d_in[8];
  const float* A1     = (const float*)d_in[9];
  const float* A2     = (const float*)d_in[10];
  const float* A3     = (const float*)d_in[11];
  const float* bA1    = (const float*)d_in[12];
  const float* bA2    = (const float*)d_in[13];
  const float* bA3    = (const float*)d_in[14];
  const float* U      = (const float*)d_in[15];
  const float* V      = (const float*)d_in[16];
  const float* bU     = (const float*)d_in[17];
  const float* bV     = (const float*)d_in[18];
  const float* bnhg   = (const float*)d_in[19];
  const float* bnhb   = (const float*)d_in[20];
  const float* bneg   = (const float*)d_in[21];
  const float* bneb   = (const float*)d_in[22];
  const float* W1     = (const float*)d_in[23];
  const float* b1     = (const float*)d_in[24];
  const float* W2     = (const float*)d_in[25];
  const float* b2     = (const float*)d_in[26];

  const int N = in_sizes[0] / 512;
  const int E = in_sizes[1];

  float* fp = (float*)d_ws;
  float* e    = fp; fp += (size_t)E * 64;
  float* h    = fp; fp += (size_t)N * 64;
  float* hhat = fp; fp += (size_t)N * 64;
  float* numb = fp; fp += (size_t)N * 64;
  float* denb = fp; fp += (size_t)N * 64;
  float* sums = fp; fp += 1024;
  unsigned short* up = (unsigned short*)fp;
  unsigned short* ehatA = up; up += (size_t)E * 64;
  unsigned short* ehatB = up; up += (size_t)E * 64;
  unsigned short* XA1 = up; up += (size_t)N * 64;
  unsigned short* XA2 = up; up += (size_t)N * 64;
  unsigned short* XV  = up; up += (size_t)N * 64;
  int* ip = (int*)up;
  int* order   = ip; ip += E;
  int* psrc    = ip; ip += E;
  int* pdst    = ip; ip += E;
  int* cnt     = ip; ip += N;
  int* nxt     = ip; ip += N;
  int* row_ptr = ip; ip += N + 1;
  float* out = (float*)d_out;

  hipMemsetAsync(cnt, 0, sizeof(int) * N, stream);
  hipMemsetAsync(sums, 0, sizeof(float) * 1024, stream);
  k_hist<<<(E + 255) / 256, 256, 0, stream>>>(dst, cnt, E);
  k_scan<<<1, 1024, 0, stream>>>(cnt, row_ptr, nxt, N, E);
  k_scatter<<<(E + 255) / 256, 256, 0, stream>>>(dst, src, nxt, order, psrc, pdst, E);

  k_conv_mfma<<<(N + 3) / 4, 256, 0, stream>>>(reads, conv_w, conv_b, h, N);
  k_edge_enc<<<(E * 16 + 255) / 256, 256, 0, stream>>>(sim, olen, order, We, be, e, E);

  const int PBLK = 1024;
  unsigned short* ehat_cur = ehatA;
  unsigned short* ehat_prev = ehatB;
  for (int l = 0; l < 4; ++l) {
    ehat_cur = (l & 1) ? ehatB : ehatA;
    ehat_prev = (l & 1) ? ehatA : ehatB;
    float* sums_e = sums + l * 128;
    float* sums_h = sums + 512 + l * 128;
    const float* sums_e_prev = sums + (l - 1) * 128;
    k_node_gemm<<<dim3((N + 255) / 256, 3), 256, 0, stream>>>(
        h, A1 + l * 4096, A2 + l * 4096, V + l * 4096,
        bA1 + l * 64, bA2 + l * 64, bV + l * 64, XA1, XA2, XV, N);
    k_edge_mfma<<<PBLK, 256, 0, stream>>>(
        e, ehat_prev, ehat_cur,
        l > 0 ? sums_e_prev : sums, bneg + (l > 0 ? (l - 1) * 64 : 0),
        bneb + (l > 0 ? (l - 1) * 64 : 0),
        psrc, pdst, XA1, XA2, A3 + l * 4096, bA3 + l * 64, sums_e, E, l > 0 ? 1 : 0);
    k_aggregate<<<(N * 16 + 255) / 256, 256, 0, stream>>>(
        row_ptr, psrc, ehat_cur, XV, numb, denb, N);
    k_hhat<<<(N + 255) / 256, 256, 0, stream>>>(
        h, U + l * 4096, bU + l * 64, numb, denb, hhat, N);
    k_stats<<<256, 256, 0, stream>>>(hhat, N, sums_h);
    k_update_h<<<(N * 16 + 255) / 256, 256, 0, stream>>>(
        h, hhat, sums_h, bnhg + l * 64, bnhb + l * 64, N);
  }

  k_decoder_mfma<<<PBLK, 256, 0, stream>>>(
      h, e, ehat_cur, sums + 3 * 128, bneg + 3 * 64, bneb + 3 * 64,
      psrc, pdst, order, W1, b1, W2, b2, out, E);
}